// Round 2
// baseline (5802.018 us; speedup 1.0000x reference)
//
#include <hip/hip_runtime.h>
#include <hip/hip_bf16.h>

// BiRNN: B=64, T=512, F=H=512, fp32 in/out.
// gemm_xw: unchanged from verified baseline (xw = x@W + b staged into out).
// rnn_rec REDESIGN (sync-latency attack):
//   - 64 WGs x 128 thr (2 waves). Wave w of WG (g,jm) owns H rows
//     [(2*jm+w)*16,+16) x cols [g*16,+16) for BOTH directions, alternating
//     dir0/dir1 every step -> each direction's barrier round-trip overlaps
//     the other direction's loads+MFMA (latency hidden regardless of RT).
//   - Sub-barriers per (dir, m-slice): 8 counters x 32 waves. Consumers of a
//     row-slice gate only on that slice's producers.
//   - NO __syncthreads in the time loop: wave-synchronous protocol
//     (stores -> s_waitcnt vmcnt(0) -> ctr add; lane0 poll -> fence -> loads).
//   - H layout: identity feature order. Lane pairs (2i,2i+1) hold adjacent
//     output cols in the MFMA C layout; shfl_xor(1) packs hi/lo bf16 pairs so
//     H stores stay proven u32 agent atomics.
//   - Exchange mechanism identical to verified baseline: agent-scope relaxed
//     atomics (sc0 sc1 LLC bypass), drain-implies-visible, relaxed ctr adds.

using bf16 = __hip_bfloat16;
typedef __attribute__((ext_vector_type(8))) short short8;   // bf16x8 MFMA frag
typedef __attribute__((ext_vector_type(4))) float float4v;  // fp32x4 acc

#define T_STEPS 512

// d_ws: [0..1023] counters: ctr[(d*4+m)] at byte (d*4+m)*128
//       [1024..] Hbuf u16: per dir 131072 elems = 2 phases x (hi 32768 + lo 32768)
#define HB_OFF  1024
#define WS_ZERO_BYTES (HB_OFF + 2 * 131072 * 2)

__device__ __forceinline__ unsigned short f2bf(float f) {
    unsigned u = __builtin_bit_cast(unsigned, f);
    u = (u + 0x7fffu + ((u >> 16) & 1u)) >> 16;
    return (unsigned short)u;
}
__device__ __forceinline__ float bf2f(unsigned short s) {
    unsigned u = ((unsigned)s) << 16;
    return __builtin_bit_cast(float, u);
}

__global__ __launch_bounds__(256) void gemm_xw(
    const float* __restrict__ x,
    const float* __restrict__ Wf, const float* __restrict__ bf_,
    const float* __restrict__ Wb, const float* __restrict__ bb_,
    float* __restrict__ out)
{
    int bid = blockIdx.x;
    int dir = bid >> 12;
    int r   = bid & 4095;
    int i   = r & 63;
    int G   = r >> 6;
    int mt  = G * 8 + (i & 7);    // 0..511
    int nt  = i >> 3;             // 0..7
    const float* W    = dir ? Wb  : Wf;
    const float* bias = dir ? bb_ : bf_;

    __shared__ __align__(16) bf16 Xl[64][40];
    __shared__ __align__(16) bf16 Wt[64][40];

    int tid  = threadIdx.x;
    int wave = tid >> 6;
    int lane = tid & 63;
    int lm   = lane & 15;
    int quad = lane >> 4;

    float4v acc[4];
    #pragma unroll
    for (int q = 0; q < 4; ++q) acc[q] = (float4v){0.f, 0.f, 0.f, 0.f};

    int row0 = mt * 64;
    int srow = tid >> 2;
    int sk8  = (tid & 3) * 8;
    int wrow = tid >> 3;
    int wn8  = (tid & 7) * 8;

    for (int kt = 0; kt < 16; ++kt) {
        int k0 = kt * 32;
        const float* xp = x + (size_t)(row0 + srow) * 512 + k0 + sk8;
        float4v xa = *(const float4v*)xp;
        float4v xb = *(const float4v*)(xp + 4);
        union { short8 v; bf16 e[8]; } ux;
        ux.e[0] = __float2bfloat16(xa.x); ux.e[1] = __float2bfloat16(xa.y);
        ux.e[2] = __float2bfloat16(xa.z); ux.e[3] = __float2bfloat16(xa.w);
        ux.e[4] = __float2bfloat16(xb.x); ux.e[5] = __float2bfloat16(xb.y);
        ux.e[6] = __float2bfloat16(xb.z); ux.e[7] = __float2bfloat16(xb.w);
        *(short8*)&Xl[srow][sk8] = ux.v;
        const float* wp = W + (size_t)(k0 + wrow) * 512 + nt * 64 + wn8;
        float4v wa = *(const float4v*)wp;
        float4v wb = *(const float4v*)(wp + 4);
        Wt[wn8 + 0][wrow] = __float2bfloat16(wa.x);
        Wt[wn8 + 1][wrow] = __float2bfloat16(wa.y);
        Wt[wn8 + 2][wrow] = __float2bfloat16(wa.z);
        Wt[wn8 + 3][wrow] = __float2bfloat16(wa.w);
        Wt[wn8 + 4][wrow] = __float2bfloat16(wb.x);
        Wt[wn8 + 5][wrow] = __float2bfloat16(wb.y);
        Wt[wn8 + 6][wrow] = __float2bfloat16(wb.z);
        Wt[wn8 + 7][wrow] = __float2bfloat16(wb.w);
        __syncthreads();

        short8 a = *(const short8*)&Xl[wave * 16 + lm][quad * 8];
        #pragma unroll
        for (int n4 = 0; n4 < 4; ++n4) {
            short8 bfr = *(const short8*)&Wt[n4 * 16 + lm][quad * 8];
            acc[n4] = __builtin_amdgcn_mfma_f32_16x16x32_bf16(a, bfr, acc[n4], 0, 0, 0);
        }
        __syncthreads();
    }

    #pragma unroll
    for (int n4 = 0; n4 < 4; ++n4) {
        int ncol = nt * 64 + n4 * 16 + lm;
        float bv = bias[ncol];
        #pragma unroll
        for (int rr = 0; rr < 4; ++rr) {
            int m = wave * 16 + quad * 4 + rr;
            int gg = row0 + m;
            int b = gg >> 9;
            int t = gg & 511;
            int tp = dir ? (511 - t) : t;
            out[((size_t)b * T_STEPS + tp) * 1024 + dir * 512 + ncol] = acc[n4][rr] + bv;
        }
    }
}

__global__ __launch_bounds__(128) void rnn_rec(
    const float* __restrict__ Uf, const float* __restrict__ Ub,
    float* __restrict__ out, unsigned char* __restrict__ ws)
{
    unsigned* ctrs = (unsigned*)ws;
    unsigned short* Hbuf = (unsigned short*)(ws + HB_OFF);

    int bid = blockIdx.x;          // 0..63
    int g   = bid & 31;            // col group: cols [g*16, g*16+16)
    int jm  = bid >> 5;            // 0..1
    int n0  = g * 16;

    int tid  = threadIdx.x;
    int wave = tid >> 6;           // 0..1
    int lane = tid & 63;
    int lm   = lane & 15;
    int quad = lane >> 4;
    int m    = jm * 2 + wave;      // m-slice 0..3 -> rows [m*16, m*16+16)
    int m0   = m * 16;

    // U slices, identity k order: Uh[d][col-lm][k] (hi bf16), Ul = residual lo
    __shared__ __align__(16) unsigned short Uh[2][16][520];
    __shared__ __align__(16) unsigned short Ul[2][16][520];

    #pragma unroll
    for (int it = 0; it < 32; ++it) {
        int idx = it * 128 + tid;              // 0..4095
        int d   = idx >> 11;
        int rem = idx & 2047;
        int k   = rem >> 2;
        int c   = (rem & 3) * 4;
        const float* U = d ? Ub : Uf;
        float4v v = *(const float4v*)(U + (size_t)k * 512 + n0 + c);
        #pragma unroll
        for (int q = 0; q < 4; ++q) {
            float f = v[q];
            unsigned short hi = f2bf(f);
            Uh[d][c + q][k] = hi;
            Ul[d][c + q][k] = f2bf(f - bf2f(hi));
        }
    }
    __syncthreads();   // only barrier; time loop below is wave-synchronous

    unsigned* ctr0 = ctrs + (0 * 4 + m) * 32;  // 128-B spaced counters
    unsigned* ctr1 = ctrs + (1 * 4 + m) * 32;

    int rowb = m0 + quad * 4;                  // C rows rowb..rowb+3
    int col  = n0 + lm;                        // C col (one per lane)
    const size_t arow = (size_t)(m0 + lm) * 512;  // A-operand row offset

    // xw for t=0, both dirs
    float xw0[4], xw1[4];
    #pragma unroll
    for (int r = 0; r < 4; ++r) {
        size_t o = ((size_t)(rowb + r) * T_STEPS + 0) * 1024 + col;
        xw0[r] = out[o];
        xw1[r] = out[o + 512];
    }

    for (int t = 0; t < T_STEPS; ++t) {
        int ph = t & 1;
        int tn = (t + 1 < T_STEPS) ? (t + 1) : t;
        unsigned tgt = 32u * (unsigned)t;
        float xw0n[4], xw1n[4];

        auto step_dir = [&](int d, unsigned* ctr, float* xw, float* xwn) {
            unsigned short* base = Hbuf + (size_t)d * 131072;
            unsigned short* Hh = base + (size_t)ph * 65536;
            unsigned short* Hl = Hh + 32768;
            unsigned short* Wh = base + (size_t)(ph ^ 1) * 65536;
            unsigned short* Wl = Wh + 32768;
            float* od = out + (size_t)d * 512;

            // prefetch next step's xw (independent of the barrier)
            #pragma unroll
            for (int r = 0; r < 4; ++r)
                xwn[r] = od[((size_t)(rowb + r) * T_STEPS + tn) * 1024 + col];

            // sub-barrier: wait for this (dir, m-slice)'s producers.
            // Round-trip is hidden behind the OTHER direction's block.
            if (lane == 0) {
                while (__hip_atomic_load(ctr, __ATOMIC_RELAXED,
                                         __HIP_MEMORY_SCOPE_AGENT) < tgt)
                    __builtin_amdgcn_s_sleep(1);
            }
            asm volatile("" ::: "memory");

            // H[m-slice rows] @ U[:,slice], split-bf16: ah@Uh + al@Uh + ah@Ul
            float4v aa = {0,0,0,0}, ab = {0,0,0,0}, ac = {0,0,0,0};
            #pragma unroll 8
            for (int kt = 0; kt < 16; ++kt) {
                int ko = kt * 32 + quad * 8;
                unsigned long long* pa = (unsigned long long*)(Hh + arow + ko);
                unsigned long long* pl = (unsigned long long*)(Hl + arow + ko);
                union { unsigned long long q[2]; short8 s; } ua, ul;
                ua.q[0] = __hip_atomic_load(pa,     __ATOMIC_RELAXED, __HIP_MEMORY_SCOPE_AGENT);
                ua.q[1] = __hip_atomic_load(pa + 1, __ATOMIC_RELAXED, __HIP_MEMORY_SCOPE_AGENT);
                ul.q[0] = __hip_atomic_load(pl,     __ATOMIC_RELAXED, __HIP_MEMORY_SCOPE_AGENT);
                ul.q[1] = __hip_atomic_load(pl + 1, __ATOMIC_RELAXED, __HIP_MEMORY_SCOPE_AGENT);
                short8 bh = *(const short8*)&Uh[d][lm][ko];
                short8 bl = *(const short8*)&Ul[d][lm][ko];
                aa = __builtin_amdgcn_mfma_f32_16x16x32_bf16(ua.s, bh, aa, 0, 0, 0);
                ab = __builtin_amdgcn_mfma_f32_16x16x32_bf16(ul.s, bh, ab, 0, 0, 0);
                ac = __builtin_amdgcn_mfma_f32_16x16x32_bf16(ua.s, bl, ac, 0, 0, 0);
            }

            float4v s = aa + ab + ac;
            float hv[4];
            #pragma unroll
            for (int r = 0; r < 4; ++r)
                hv[r] = tanhf(s[r] + xw[r]);

            // pack lane-pair (cols 2i,2i+1 share rows) into dwords; even
            // lanes store hi/lo words with proven u32 agent atomics (-> LLC)
            #pragma unroll
            for (int r = 0; r < 4; ++r) {
                unsigned short hb = f2bf(hv[r]);
                unsigned short lb = f2bf(hv[r] - bf2f(hb));
                unsigned myw = (unsigned)hb | ((unsigned)lb << 16);
                unsigned p = (unsigned)__shfl_xor((int)myw, 1);
                if (!(lane & 1)) {
                    unsigned hiw = (myw & 0xFFFFu) | (p << 16);
                    unsigned low = (myw >> 16) | (p & 0xFFFF0000u);
                    size_t off = (size_t)(rowb + r) * 512 + col;  // col even
                    __hip_atomic_store((unsigned*)(Wh + off), hiw,
                                       __ATOMIC_RELAXED, __HIP_MEMORY_SCOPE_AGENT);
                    __hip_atomic_store((unsigned*)(Wl + off), low,
                                       __ATOMIC_RELAXED, __HIP_MEMORY_SCOPE_AGENT);
                }
            }

            // drain: H stores are at LLC before the counter add issues
            asm volatile("s_waitcnt vmcnt(0)" ::: "memory");
            if (lane == 0)
                __hip_atomic_fetch_add(ctr, 1u, __ATOMIC_RELAXED,
                                       __HIP_MEMORY_SCOPE_AGENT);

            // out writes AFTER the add: they don't gate the barrier
            #pragma unroll
            for (int r = 0; r < 4; ++r)
                od[((size_t)(rowb + r) * T_STEPS + t) * 1024 + col] = hv[r];
        };

        step_dir(0, ctr0, xw0, xw0n);
        step_dir(1, ctr1, xw1, xw1n);

        #pragma unroll
        for (int r = 0; r < 4; ++r) { xw0[r] = xw0n[r]; xw1[r] = xw1n[r]; }
    }
}

extern "C" void kernel_launch(void* const* d_in, const int* in_sizes, int n_in,
                              void* d_out, int out_size, void* d_ws, size_t ws_size,
                              hipStream_t stream) {
    const float* x   = (const float*)d_in[0];
    const float* Wf  = (const float*)d_in[1];
    const float* Uf  = (const float*)d_in[2];
    const float* bf_ = (const float*)d_in[3];
    const float* Wb  = (const float*)d_in[4];
    const float* Ub  = (const float*)d_in[5];
    const float* bb_ = (const float*)d_in[6];
    float* out = (float*)d_out;

    hipMemsetAsync(d_ws, 0, WS_ZERO_BYTES, stream);
    hipLaunchKernelGGL(gemm_xw, dim3(8192), dim3(256), 0, stream,
                       x, Wf, bf_, Wb, bb_, out);
    hipLaunchKernelGGL(rnn_rec, dim3(64), dim3(128), 0, stream,
                       Uf, Ub, out, (unsigned char*)d_ws);
}

// Round 3
// 4252.550 us; speedup vs baseline: 1.3644x; 1.3644x over previous
//
#include <hip/hip_runtime.h>
#include <hip/hip_bf16.h>

// BiRNN: B=64, T=512, F=H=512, fp32 in/out.
// gemm_xw: unchanged verified baseline (xw = x@W + b staged into out).
// rnn_rec v3 (chain-shortening):
//   - 128 WGs x 128 thr. WG=(g,m): cols [g*16,+16), rows [m*16,+16).
//     Wave 0 runs dir0, wave 1 runs dir1 -> two independent recurrence
//     chains overlap via wave TLP on the CU (not serialized in-wave).
//   - U slice held in REGISTERS (hi+lo short8[16] = 128 VGPRs/wave).
//     ZERO LDS in the kernel: no ds_read on the serial path, no bank
//     conflicts (was 1.68e7 conflict-cycles/dispatch).
//   - Producer->consumer sync via per-(dir,m) FLAG WORDS (plain bypass
//     stores to 32 distinct dwords of one 128B line; no RMW contention).
//     Consumers poll with one 32-lane agent-atomic load + __all, no sleep.
//   - Exchange path unchanged from verified baseline: agent-scope relaxed
//     atomics (sc0 sc1 -> LLC), store -> vmcnt(0) drain -> flag publish.

using bf16 = __hip_bfloat16;
typedef __attribute__((ext_vector_type(8))) short short8;   // bf16x8 MFMA frag
typedef __attribute__((ext_vector_type(4))) float float4v;  // fp32x4 acc

#define T_STEPS 512

// d_ws layout:
//   [0..1023]   flags u32: group (dir*4+m) base at byte (dir*4+m)*128, word g
//   [1024..]    Hbuf u16: per dir 131072 elems = 2 phases x (hi 32768 + lo 32768)
#define HB_OFF  1024
#define WS_ZERO_BYTES (HB_OFF + 2 * 131072 * 2)

__device__ __forceinline__ unsigned short f2bf(float f) {
    unsigned u = __builtin_bit_cast(unsigned, f);
    u = (u + 0x7fffu + ((u >> 16) & 1u)) >> 16;
    return (unsigned short)u;
}
__device__ __forceinline__ float bf2f(unsigned short s) {
    unsigned u = ((unsigned)s) << 16;
    return __builtin_bit_cast(float, u);
}

__global__ __launch_bounds__(256) void gemm_xw(
    const float* __restrict__ x,
    const float* __restrict__ Wf, const float* __restrict__ bf_,
    const float* __restrict__ Wb, const float* __restrict__ bb_,
    float* __restrict__ out)
{
    int bid = blockIdx.x;
    int dir = bid >> 12;
    int r   = bid & 4095;
    int i   = r & 63;
    int G   = r >> 6;
    int mt  = G * 8 + (i & 7);    // 0..511
    int nt  = i >> 3;             // 0..7
    const float* W    = dir ? Wb  : Wf;
    const float* bias = dir ? bb_ : bf_;

    __shared__ __align__(16) bf16 Xl[64][40];
    __shared__ __align__(16) bf16 Wt[64][40];

    int tid  = threadIdx.x;
    int wave = tid >> 6;
    int lane = tid & 63;
    int lm   = lane & 15;
    int quad = lane >> 4;

    float4v acc[4];
    #pragma unroll
    for (int q = 0; q < 4; ++q) acc[q] = (float4v){0.f, 0.f, 0.f, 0.f};

    int row0 = mt * 64;
    int srow = tid >> 2;
    int sk8  = (tid & 3) * 8;
    int wrow = tid >> 3;
    int wn8  = (tid & 7) * 8;

    for (int kt = 0; kt < 16; ++kt) {
        int k0 = kt * 32;
        const float* xp = x + (size_t)(row0 + srow) * 512 + k0 + sk8;
        float4v xa = *(const float4v*)xp;
        float4v xb = *(const float4v*)(xp + 4);
        union { short8 v; bf16 e[8]; } ux;
        ux.e[0] = __float2bfloat16(xa.x); ux.e[1] = __float2bfloat16(xa.y);
        ux.e[2] = __float2bfloat16(xa.z); ux.e[3] = __float2bfloat16(xa.w);
        ux.e[4] = __float2bfloat16(xb.x); ux.e[5] = __float2bfloat16(xb.y);
        ux.e[6] = __float2bfloat16(xb.z); ux.e[7] = __float2bfloat16(xb.w);
        *(short8*)&Xl[srow][sk8] = ux.v;
        const float* wp = W + (size_t)(k0 + wrow) * 512 + nt * 64 + wn8;
        float4v wa = *(const float4v*)wp;
        float4v wb = *(const float4v*)(wp + 4);
        Wt[wn8 + 0][wrow] = __float2bfloat16(wa.x);
        Wt[wn8 + 1][wrow] = __float2bfloat16(wa.y);
        Wt[wn8 + 2][wrow] = __float2bfloat16(wa.z);
        Wt[wn8 + 3][wrow] = __float2bfloat16(wa.w);
        Wt[wn8 + 4][wrow] = __float2bfloat16(wb.x);
        Wt[wn8 + 5][wrow] = __float2bfloat16(wb.y);
        Wt[wn8 + 6][wrow] = __float2bfloat16(wb.z);
        Wt[wn8 + 7][wrow] = __float2bfloat16(wb.w);
        __syncthreads();

        short8 a = *(const short8*)&Xl[wave * 16 + lm][quad * 8];
        #pragma unroll
        for (int n4 = 0; n4 < 4; ++n4) {
            short8 bfr = *(const short8*)&Wt[n4 * 16 + lm][quad * 8];
            acc[n4] = __builtin_amdgcn_mfma_f32_16x16x32_bf16(a, bfr, acc[n4], 0, 0, 0);
        }
        __syncthreads();
    }

    #pragma unroll
    for (int n4 = 0; n4 < 4; ++n4) {
        int ncol = nt * 64 + n4 * 16 + lm;
        float bv = bias[ncol];
        #pragma unroll
        for (int rr = 0; rr < 4; ++rr) {
            int m = wave * 16 + quad * 4 + rr;
            int gg = row0 + m;
            int b = gg >> 9;
            int t = gg & 511;
            int tp = dir ? (511 - t) : t;
            out[((size_t)b * T_STEPS + tp) * 1024 + dir * 512 + ncol] = acc[n4][rr] + bv;
        }
    }
}

__global__ __launch_bounds__(128, 1) void rnn_rec(
    const float* __restrict__ Uf, const float* __restrict__ Ub,
    float* __restrict__ out, unsigned char* __restrict__ ws)
{
    unsigned* flags = (unsigned*)ws;
    unsigned short* Hbuf = (unsigned short*)(ws + HB_OFF);

    int bid = blockIdx.x;          // 0..127
    int g   = bid & 31;            // col group: cols [g*16, g*16+16)
    int m   = bid >> 5;            // 0..3: rows [m*16, m*16+16)
    int n0  = g * 16;
    int m0  = m * 16;

    int tid  = threadIdx.x;
    int dir  = tid >> 6;           // wave 0 -> dir0, wave 1 -> dir1
    int lane = tid & 63;
    int lm   = lane & 15;
    int quad = lane >> 4;

    const float* U = dir ? Ub : Uf;

    // ---- U slice into registers: B-frag per kt, hi + lo residual ----
    // lane (lm,quad) holds B[k = kt*32 + quad*8 + j][n0+lm], j=0..7
    short8 Bh[16], Bl[16];
    #pragma unroll
    for (int kt = 0; kt < 16; ++kt) {
        union { short8 v; unsigned short e[8]; } h, l;
        #pragma unroll
        for (int j = 0; j < 8; ++j) {
            int k = kt * 32 + quad * 8 + j;
            float f = U[(size_t)k * 512 + n0 + lm];
            unsigned short hi = f2bf(f);
            h.e[j] = hi;
            l.e[j] = f2bf(f - bf2f(hi));
        }
        Bh[kt] = h.v;
        Bl[kt] = l.v;
    }

    unsigned* fbase = flags + (dir * 4 + m) * 32;   // this group's 32 flags
    unsigned short* base = Hbuf + (size_t)dir * 131072;
    float* od = out + (size_t)dir * 512;

    int rowb = m0 + quad * 4;                  // C rows rowb..rowb+3
    int col  = n0 + lm;                        // C col (one per lane)
    const size_t arow = (size_t)(m0 + lm) * 512;  // A-operand row offset

    // xw for t=0
    float xw[4];
    #pragma unroll
    for (int r = 0; r < 4; ++r)
        xw[r] = od[((size_t)(rowb + r) * T_STEPS + 0) * 1024 + col];

    for (int t = 0; t < T_STEPS; ++t) {
        int ph = t & 1;
        unsigned short* Hh = base + (size_t)ph * 65536;
        unsigned short* Hl = Hh + 32768;
        unsigned short* Wh = base + (size_t)(ph ^ 1) * 65536;
        unsigned short* Wl = Wh + 32768;

        // ---- poll: all 32 producers of (dir,m) have published step t-1 ----
        if (t) {
            unsigned tgt = (unsigned)t;
            unsigned f;
            do {
                f = (lane < 32)
                  ? __hip_atomic_load(fbase + lane, __ATOMIC_RELAXED,
                                      __HIP_MEMORY_SCOPE_AGENT)
                  : tgt;
            } while (!__all(f >= tgt));
        }

        // ---- H[m-slice rows] @ U[:,slice], split-bf16 ----
        float4v aa = {0,0,0,0}, ab = {0,0,0,0}, ac = {0,0,0,0};
        #pragma unroll
        for (int kt = 0; kt < 16; ++kt) {
            int ko = kt * 32 + quad * 8;
            unsigned long long* pa = (unsigned long long*)(Hh + arow + ko);
            unsigned long long* pl = (unsigned long long*)(Hl + arow + ko);
            union { unsigned long long q[2]; short8 s; } ua, ul;
            ua.q[0] = __hip_atomic_load(pa,     __ATOMIC_RELAXED, __HIP_MEMORY_SCOPE_AGENT);
            ua.q[1] = __hip_atomic_load(pa + 1, __ATOMIC_RELAXED, __HIP_MEMORY_SCOPE_AGENT);
            ul.q[0] = __hip_atomic_load(pl,     __ATOMIC_RELAXED, __HIP_MEMORY_SCOPE_AGENT);
            ul.q[1] = __hip_atomic_load(pl + 1, __ATOMIC_RELAXED, __HIP_MEMORY_SCOPE_AGENT);
            aa = __builtin_amdgcn_mfma_f32_16x16x32_bf16(ua.s, Bh[kt], aa, 0, 0, 0);
            ab = __builtin_amdgcn_mfma_f32_16x16x32_bf16(ul.s, Bh[kt], ab, 0, 0, 0);
            ac = __builtin_amdgcn_mfma_f32_16x16x32_bf16(ua.s, Bl[kt], ac, 0, 0, 0);
        }

        float4v s = aa + ab + ac;
        float hv[4];
        #pragma unroll
        for (int r = 0; r < 4; ++r)
            hv[r] = tanhf(s[r] + xw[r]);

        // ---- H publish: lane-pair pack -> u32 agent-atomic bypass stores ----
        #pragma unroll
        for (int r = 0; r < 4; ++r) {
            unsigned short hb = f2bf(hv[r]);
            unsigned short lb = f2bf(hv[r] - bf2f(hb));
            unsigned myw = (unsigned)hb | ((unsigned)lb << 16);
            unsigned p = (unsigned)__shfl_xor((int)myw, 1);
            if (!(lane & 1)) {
                unsigned hiw = (myw & 0xFFFFu) | (p << 16);
                unsigned low = (myw >> 16) | (p & 0xFFFF0000u);
                size_t off = (size_t)(rowb + r) * 512 + col;  // col even
                __hip_atomic_store((unsigned*)(Wh + off), hiw,
                                   __ATOMIC_RELAXED, __HIP_MEMORY_SCOPE_AGENT);
                __hip_atomic_store((unsigned*)(Wl + off), low,
                                   __ATOMIC_RELAXED, __HIP_MEMORY_SCOPE_AGENT);
            }
        }

        // drain: H stores are at LLC before the flag publishes
        asm volatile("s_waitcnt vmcnt(0)" ::: "memory");
        if (lane == 0)
            __hip_atomic_store(fbase + g, (unsigned)(t + 1),
                               __ATOMIC_RELAXED, __HIP_MEMORY_SCOPE_AGENT);

        // out writes + next-step xw prefetch AFTER the publish
        #pragma unroll
        for (int r = 0; r < 4; ++r)
            od[((size_t)(rowb + r) * T_STEPS + t) * 1024 + col] = hv[r];

        int tn = (t + 1 < T_STEPS) ? (t + 1) : t;
        #pragma unroll
        for (int r = 0; r < 4; ++r)
            xw[r] = od[((size_t)(rowb + r) * T_STEPS + tn) * 1024 + col];
    }
}

extern "C" void kernel_launch(void* const* d_in, const int* in_sizes, int n_in,
                              void* d_out, int out_size, void* d_ws, size_t ws_size,
                              hipStream_t stream) {
    const float* x   = (const float*)d_in[0];
    const float* Wf  = (const float*)d_in[1];
    const float* Uf  = (const float*)d_in[2];
    const float* bf_ = (const float*)d_in[3];
    const float* Wb  = (const float*)d_in[4];
    const float* Ub  = (const float*)d_in[5];
    const float* bb_ = (const float*)d_in[6];
    float* out = (float*)d_out;

    hipMemsetAsync(d_ws, 0, WS_ZERO_BYTES, stream);
    hipLaunchKernelGGL(gemm_xw, dim3(8192), dim3(256), 0, stream,
                       x, Wf, bf_, Wb, bb_, out);
    hipLaunchKernelGGL(rnn_rec, dim3(128), dim3(128), 0, stream,
                       Uf, Ub, out, (unsigned char*)d_ws);
}

// Round 6
// 3774.355 us; speedup vs baseline: 1.5372x; 1.1267x over previous
//
#include <hip/hip_runtime.h>
#include <hip/hip_bf16.h>

// BiRNN: B=64, T=512, F=H=512, fp32 in/out.
// gemm_xw: verified baseline + epoch bump (one atomic add, block 0).
// rnn_rec v6 (XCD-local reads, hang-proof):
//   - Sharding as v3/v5: 128 WGs x 128 thr, group=(dir,m)=bid&7 (16 WGs,
//     32 waves), wave owns 16 rows x 16 cols of one dir.
//   - ALL stores (H, flags) = v3-proven agent-scope atomics (sc0 sc1:
//     through local L2 to LLC). Only consumer LOADS differ in fast mode:
//     inline-asm sc0 (bypass L1, hit local L2 which the write-through
//     updated). Wrong-placement or wrong-L2-assumption => wrong results
//     (visible absmax), NEVER a hang.
//   - Bounded fast poll (<=128 spins) with STICKY downgrade to the v3
//     agent protocol => deadlock impossible in all worlds.
//   - Epoch-versioned flags (epoch lives OUTSIDE the memset window,
//     bumped by gemm_xw; windowed compare) => stale cache lines from
//     prior launches can never false-pass.
//   - t=0: h = tanh(xw) directly (H0=0); no Hbuf memset, no t=0 loads.
//   - U hi-plane in 64 VGPRs; lo-plane in conflict-free LDS (32 KiB).

using bf16 = __hip_bfloat16;
typedef __attribute__((ext_vector_type(8))) short short8;   // bf16x8 MFMA frag
typedef __attribute__((ext_vector_type(4))) float float4v;  // fp32x4 acc

#define T_STEPS 512

// d_ws layout:
//   [0..1023]    flags u32: group grp base at byte grp*128, word g (0..31)
//   [1024..1535] xcc table u32[128]
//   [1536..1663] grid-barrier counter
//   [1664..1667] epoch u32 (NOT zeroed by memset; persists across launches)
//   [2048..]     Hbuf u16: per dir 131072 = 2 phases x (hi 32768 + lo 32768)
#define HB_OFF  2048
#define WS_HDR_ZERO 1664

__device__ __forceinline__ unsigned short f2bf(float f) {
    unsigned u = __builtin_bit_cast(unsigned, f);
    u = (u + 0x7fffu + ((u >> 16) & 1u)) >> 16;
    return (unsigned short)u;
}
__device__ __forceinline__ float bf2f(unsigned short s) {
    unsigned u = ((unsigned)s) << 16;
    return __builtin_bit_cast(float, u);
}

__global__ __launch_bounds__(256) void gemm_xw(
    const float* __restrict__ x,
    const float* __restrict__ Wf, const float* __restrict__ bf_,
    const float* __restrict__ Wb, const float* __restrict__ bb_,
    float* __restrict__ out, unsigned char* __restrict__ ws)
{
    int bid = blockIdx.x;
    if (bid == 0 && threadIdx.x == 0) {
        // bump launch epoch (read by rnn_rec after this kernel completes)
        __hip_atomic_fetch_add((unsigned*)(ws + 1664), 1u,
                               __ATOMIC_RELAXED, __HIP_MEMORY_SCOPE_AGENT);
    }
    int dir = bid >> 12;
    int r   = bid & 4095;
    int i   = r & 63;
    int G   = r >> 6;
    int mt  = G * 8 + (i & 7);    // 0..511
    int nt  = i >> 3;             // 0..7
    const float* W    = dir ? Wb  : Wf;
    const float* bias = dir ? bb_ : bf_;

    __shared__ __align__(16) bf16 Xl[64][40];
    __shared__ __align__(16) bf16 Wt[64][40];

    int tid  = threadIdx.x;
    int wave = tid >> 6;
    int lane = tid & 63;
    int lm   = lane & 15;
    int quad = lane >> 4;

    float4v acc[4];
    #pragma unroll
    for (int q = 0; q < 4; ++q) acc[q] = (float4v){0.f, 0.f, 0.f, 0.f};

    int row0 = mt * 64;
    int srow = tid >> 2;
    int sk8  = (tid & 3) * 8;
    int wrow = tid >> 3;
    int wn8  = (tid & 7) * 8;

    for (int kt = 0; kt < 16; ++kt) {
        int k0 = kt * 32;
        const float* xp = x + (size_t)(row0 + srow) * 512 + k0 + sk8;
        float4v xa = *(const float4v*)xp;
        float4v xb = *(const float4v*)(xp + 4);
        union { short8 v; bf16 e[8]; } ux;
        ux.e[0] = __float2bfloat16(xa.x); ux.e[1] = __float2bfloat16(xa.y);
        ux.e[2] = __float2bfloat16(xa.z); ux.e[3] = __float2bfloat16(xa.w);
        ux.e[4] = __float2bfloat16(xb.x); ux.e[5] = __float2bfloat16(xb.y);
        ux.e[6] = __float2bfloat16(xb.z); ux.e[7] = __float2bfloat16(xb.w);
        *(short8*)&Xl[srow][sk8] = ux.v;
        const float* wp = W + (size_t)(k0 + wrow) * 512 + nt * 64 + wn8;
        float4v wa = *(const float4v*)wp;
        float4v wb = *(const float4v*)(wp + 4);
        Wt[wn8 + 0][wrow] = __float2bfloat16(wa.x);
        Wt[wn8 + 1][wrow] = __float2bfloat16(wa.y);
        Wt[wn8 + 2][wrow] = __float2bfloat16(wa.z);
        Wt[wn8 + 3][wrow] = __float2bfloat16(wa.w);
        Wt[wn8 + 4][wrow] = __float2bfloat16(wb.x);
        Wt[wn8 + 5][wrow] = __float2bfloat16(wb.y);
        Wt[wn8 + 6][wrow] = __float2bfloat16(wb.z);
        Wt[wn8 + 7][wrow] = __float2bfloat16(wb.w);
        __syncthreads();

        short8 a = *(const short8*)&Xl[wave * 16 + lm][quad * 8];
        #pragma unroll
        for (int n4 = 0; n4 < 4; ++n4) {
            short8 bfr = *(const short8*)&Wt[n4 * 16 + lm][quad * 8];
            acc[n4] = __builtin_amdgcn_mfma_f32_16x16x32_bf16(a, bfr, acc[n4], 0, 0, 0);
        }
        __syncthreads();
    }

    #pragma unroll
    for (int n4 = 0; n4 < 4; ++n4) {
        int ncol = nt * 64 + n4 * 16 + lm;
        float bv = bias[ncol];
        #pragma unroll
        for (int rr = 0; rr < 4; ++rr) {
            int mm = wave * 16 + quad * 4 + rr;
            int gg = row0 + mm;
            int b = gg >> 9;
            int t = gg & 511;
            int tp = dir ? (511 - t) : t;
            out[((size_t)b * T_STEPS + tp) * 1024 + dir * 512 + ncol] = acc[n4][rr] + bv;
        }
    }
}

__global__ __launch_bounds__(128, 1) void rnn_rec(
    const float* __restrict__ Uf, const float* __restrict__ Ub,
    float* __restrict__ out, unsigned char* __restrict__ ws)
{
    unsigned* flags = (unsigned*)ws;
    unsigned* xcct  = (unsigned*)(ws + 1024);
    unsigned* barc  = (unsigned*)(ws + 1536);
    unsigned short* Hbuf = (unsigned short*)(ws + HB_OFF);

    int bid = blockIdx.x;          // 0..127
    int grp = bid & 7;             // group = (dir,m)
    int dir = grp >> 2;
    int m   = grp & 3;
    int j   = bid >> 3;            // 0..15: WG index within group

    int tid  = threadIdx.x;
    int wv   = tid >> 6;           // 0..1
    int lane = tid & 63;
    int lm   = lane & 15;
    int quad = lane >> 4;
    int g    = j * 2 + wv;         // col group 0..31: cols [g*16,+16)
    int n0   = g * 16;
    int m0   = m * 16;

    // epoch for this launch (gemm_xw bumped it; dispatch-boundary visible)
    unsigned ep = __hip_atomic_load((unsigned*)(ws + 1664),
                                    __ATOMIC_RELAXED, __HIP_MEMORY_SCOPE_AGENT);
    unsigned ebase = ep << 10;     // flag values: ebase + t + 1

    // ---- publish XCC_ID (tagged) + arrive at grid barrier ----
    if (tid == 0) {
        unsigned xid = __builtin_amdgcn_s_getreg(20 | (0 << 6) | (31 << 11)) & 0xffu;
        __hip_atomic_store(xcct + bid, xid | 0x100u,
                           __ATOMIC_RELAXED, __HIP_MEMORY_SCOPE_AGENT);
        __hip_atomic_fetch_add(barc, 1u, __ATOMIC_RELAXED, __HIP_MEMORY_SCOPE_AGENT);
    }

    const float* U = dir ? Ub : Uf;

    // ---- U slice: hi plane -> 64 VGPRs, lo plane -> conflict-free LDS ----
    __shared__ __align__(16) short8 BlLds[2][16][64];   // 32 KiB
    short8 Bh[16];
    #pragma unroll
    for (int kt = 0; kt < 16; ++kt) {
        union { short8 v; unsigned short e[8]; } h, l;
        #pragma unroll
        for (int jj = 0; jj < 8; ++jj) {
            int k = kt * 32 + quad * 8 + jj;
            float f = U[(size_t)k * 512 + n0 + lm];
            unsigned short hi = f2bf(f);
            h.e[jj] = hi;
            l.e[jj] = f2bf(f - bf2f(hi));
        }
        Bh[kt] = h.v;
        BlLds[wv][kt][lane] = l.v;   // own slot; only this wave reads it
    }

    unsigned* fbase = flags + grp * 32;
    unsigned short* base = Hbuf + (size_t)dir * 131072;
    float* od = out + (size_t)dir * 512;

    int rowb = m0 + quad * 4;
    int col  = n0 + lm;
    const size_t arow = (size_t)(m0 + lm) * 512;

    float xwl[4];
    #pragma unroll
    for (int r = 0; r < 4; ++r)
        xwl[r] = od[((size_t)(rowb + r) * T_STEPS + 0) * 1024 + col];

    // ---- grid barrier (co-residency proven by v2/v3 flag protocols) ----
    if (tid == 0) {
        while (__hip_atomic_load(barc, __ATOMIC_RELAXED,
                                 __HIP_MEMORY_SCOPE_AGENT) < 128u)
            __builtin_amdgcn_s_sleep(2);
    }
    __syncthreads();

    // ---- placement check -> uniform per-group 'fast' ----
    unsigned e = (lane < 16)
        ? __hip_atomic_load(xcct + grp + 8 * (lane & 15),
                            __ATOMIC_RELAXED, __HIP_MEMORY_SCOPE_AGENT)
        : 0u;
    unsigned e0 = (unsigned)__shfl((int)e, 0);
    bool same = __all((lane < 16) ? (e == e0) : 1);
    unsigned eo = (lane == 0)
        ? __hip_atomic_load(xcct + ((grp + 1) & 7),
                            __ATOMIC_RELAXED, __HIP_MEMORY_SCOPE_AGENT)
        : 0u;
    eo = (unsigned)__shfl((int)eo, 0);
    bool safe_mode = !(same && (eo != e0));   // sticky; may flip true on timeout

    for (int t = 0; t < T_STEPS; ++t) {
        int ph = t & 1;
        unsigned short* Hh = base + (size_t)ph * 65536;
        unsigned short* Hl = Hh + 32768;
        unsigned short* Wh = base + (size_t)(ph ^ 1) * 65536;
        unsigned short* Wl = Wh + 32768;

        float4v aa = {0,0,0,0}, ab = {0,0,0,0}, ac = {0,0,0,0};

        if (t) {
            unsigned tgt = ebase + (unsigned)t;   // producers published t-1

            // ---- poll: windowed compare kills stale-epoch lines ----
            if (!safe_mode) {
                const unsigned* fp = fbase + (lane & 31);
                unsigned fv;
                bool ok = false;
                int spins = 0;
                do {
                    asm volatile(
                        "global_load_dword %0, %1, off sc0\n\t"
                        "s_waitcnt vmcnt(0)"
                        : "=v"(fv) : "v"(fp) : "memory");
                    __builtin_amdgcn_sched_barrier(0);
                    ok = __all((fv - tgt) < 1024u);
                } while (!ok && ++spins < 128);
                if (!ok) safe_mode = true;        // sticky downgrade, no hang
            }
            if (safe_mode) {
                unsigned fv;
                do {
                    fv = (lane < 32)
                       ? __hip_atomic_load(fbase + lane, __ATOMIC_RELAXED,
                                           __HIP_MEMORY_SCOPE_AGENT)
                       : tgt;
                } while (!__all((fv - tgt) < 1024u));
            }

            // ---- H[m-rows] @ U[:,cols], split-bf16 (3 products) ----
            if (!safe_mode) {
                // quarter-pipelined sc0 loads (L2-local); constant vmcnt waits
                asm volatile("s_waitcnt vmcnt(0)" ::: "memory");
                short8 ha[3][4], la[3][4];
                auto issueq = [&](int q, int buf) {
                    #pragma unroll
                    for (int i = 0; i < 4; ++i) {
                        int kt = q * 4 + i;
                        const unsigned short* pa = Hh + arow + kt * 32 + quad * 8;
                        const unsigned short* pl = Hl + arow + kt * 32 + quad * 8;
                        asm volatile("global_load_dwordx4 %0, %1, off sc0"
                                     : "=v"(ha[buf][i]) : "v"(pa) : "memory");
                        asm volatile("global_load_dwordx4 %0, %1, off sc0"
                                     : "=v"(la[buf][i]) : "v"(pl) : "memory");
                    }
                };
                auto compq = [&](int q, int buf) {
                    short8 blv[4];
                    #pragma unroll
                    for (int i = 0; i < 4; ++i)
                        blv[i] = BlLds[wv][q * 4 + i][lane];
                    #pragma unroll
                    for (int i = 0; i < 4; ++i) {
                        int kt = q * 4 + i;
                        aa = __builtin_amdgcn_mfma_f32_16x16x32_bf16(ha[buf][i], Bh[kt], aa, 0, 0, 0);
                        ab = __builtin_amdgcn_mfma_f32_16x16x32_bf16(la[buf][i], Bh[kt], ab, 0, 0, 0);
                        ac = __builtin_amdgcn_mfma_f32_16x16x32_bf16(ha[buf][i], blv[i], ac, 0, 0, 0);
                    }
                };
                issueq(0, 0); issueq(1, 1);
                asm volatile("s_waitcnt vmcnt(8)" ::: "memory");
                __builtin_amdgcn_sched_barrier(0);
                compq(0, 0); issueq(2, 2);
                asm volatile("s_waitcnt vmcnt(8)" ::: "memory");
                __builtin_amdgcn_sched_barrier(0);
                compq(1, 1); issueq(3, 0);
                asm volatile("s_waitcnt vmcnt(8)" ::: "memory");
                __builtin_amdgcn_sched_barrier(0);
                compq(2, 2);
                asm volatile("s_waitcnt vmcnt(0)" ::: "memory");
                __builtin_amdgcn_sched_barrier(0);
                compq(3, 0);
            } else {
                #pragma unroll
                for (int kt = 0; kt < 16; ++kt) {
                    int ko = kt * 32 + quad * 8;
                    unsigned long long* pa = (unsigned long long*)(Hh + arow + ko);
                    unsigned long long* pl = (unsigned long long*)(Hl + arow + ko);
                    union { unsigned long long q[2]; short8 s; } ua, ul;
                    ua.q[0] = __hip_atomic_load(pa,     __ATOMIC_RELAXED, __HIP_MEMORY_SCOPE_AGENT);
                    ua.q[1] = __hip_atomic_load(pa + 1, __ATOMIC_RELAXED, __HIP_MEMORY_SCOPE_AGENT);
                    ul.q[0] = __hip_atomic_load(pl,     __ATOMIC_RELAXED, __HIP_MEMORY_SCOPE_AGENT);
                    ul.q[1] = __hip_atomic_load(pl + 1, __ATOMIC_RELAXED, __HIP_MEMORY_SCOPE_AGENT);
                    short8 blv = BlLds[wv][kt][lane];
                    aa = __builtin_amdgcn_mfma_f32_16x16x32_bf16(ua.s, Bh[kt], aa, 0, 0, 0);
                    ab = __builtin_amdgcn_mfma_f32_16x16x32_bf16(ul.s, Bh[kt], ab, 0, 0, 0);
                    ac = __builtin_amdgcn_mfma_f32_16x16x32_bf16(ua.s, blv,    ac, 0, 0, 0);
                }
            }
        }
        // t == 0: s = 0 => h = tanh(xw); no loads, no Hbuf zeroing needed

        float4v s = aa + ab + ac;
        float hv[4];
        #pragma unroll
        for (int r = 0; r < 4; ++r)
            hv[r] = tanhf(s[r] + xwl[r]);

        // ---- H publish: lane-pair pack -> u32 agent stores (v3-proven) ----
        #pragma unroll
        for (int r = 0; r < 4; ++r) {
            unsigned short hb = f2bf(hv[r]);
            unsigned short lb = f2bf(hv[r] - bf2f(hb));
            unsigned myw = (unsigned)hb | ((unsigned)lb << 16);
            unsigned p = (unsigned)__shfl_xor((int)myw, 1);
            if (!(lane & 1)) {
                unsigned hiw = (myw & 0xFFFFu) | (p << 16);
                unsigned low = (myw >> 16) | (p & 0xFFFF0000u);
                size_t off = (size_t)(rowb + r) * 512 + col;  // col even
                __hip_atomic_store((unsigned*)(Wh + off), hiw,
                                   __ATOMIC_RELAXED, __HIP_MEMORY_SCOPE_AGENT);
                __hip_atomic_store((unsigned*)(Wl + off), low,
                                   __ATOMIC_RELAXED, __HIP_MEMORY_SCOPE_AGENT);
            }
        }

        // drain: H stores committed (updated local L2 en route to LLC)
        asm volatile("s_waitcnt vmcnt(0)" ::: "memory");
        if (lane == 0)
            __hip_atomic_store(fbase + g, ebase + (unsigned)(t + 1),
                               __ATOMIC_RELAXED, __HIP_MEMORY_SCOPE_AGENT);

        // out writes + next xw prefetch AFTER publish (off the sync chain)
        #pragma unroll
        for (int r = 0; r < 4; ++r)
            od[((size_t)(rowb + r) * T_STEPS + t) * 1024 + col] = hv[r];

        int tn = (t + 1 < T_STEPS) ? (t + 1) : t;
        #pragma unroll
        for (int r = 0; r < 4; ++r)
            xwl[r] = od[((size_t)(rowb + r) * T_STEPS + tn) * 1024 + col];
    }
}

extern "C" void kernel_launch(void* const* d_in, const int* in_sizes, int n_in,
                              void* d_out, int out_size, void* d_ws, size_t ws_size,
                              hipStream_t stream) {
    const float* x   = (const float*)d_in[0];
    const float* Wf  = (const float*)d_in[1];
    const float* Uf  = (const float*)d_in[2];
    const float* bf_ = (const float*)d_in[3];
    const float* Wb  = (const float*)d_in[4];
    const float* Ub  = (const float*)d_in[5];
    const float* bb_ = (const float*)d_in[6];
    float* out = (float*)d_out;

    // zero flags + xcc table + barrier ONLY; epoch (byte 1664) persists,
    // Hbuf needs no zeroing (t=0 computes h=tanh(xw) without loads).
    hipMemsetAsync(d_ws, 0, WS_HDR_ZERO, stream);
    hipLaunchKernelGGL(gemm_xw, dim3(8192), dim3(256), 0, stream,
                       x, Wf, bf_, Wb, bb_, out, (unsigned char*)d_ws);
    hipLaunchKernelGGL(rnn_rec, dim3(128), dim3(128), 0, stream,
                       Uf, Ub, out, (unsigned char*)d_ws);
}